// Round 2
// baseline (1430.180 us; speedup 1.0000x reference)
//
#include <hip/hip_runtime.h>

#define I_DIM 2304
#define J_DIM 32
#define D_IN  8
#define E_DIM 16
#define B_DIM 64
#define BB    8            // b's per block (8 half-waves of a 256-thread block)
#define NCHUNK 128
#define CHUNK (I_DIM / NCHUNK)   // 18 i's per block

// One half-wave (32 lanes) owns one (b, i): lane = j.
// Lane holds u_hat[j][0:16] in regs; softmax over j = shfl over 32 lanes.
__global__ __launch_bounds__(256) void caps_pass(
    const float* __restrict__ x,    // [B, I, 8]
    const float* __restrict__ W,    // [I, J, 8, 16]
    const float* __restrict__ b0,   // [I, J]
    const float* __restrict__ Vacc, // [B, J, 16]  (sum of V from prior iters)
    float* __restrict__ S)          // [B, J, 16]  (output accumulators, pre-zeroed)
{
    const int tid   = threadIdx.x;
    const int hw    = tid >> 5;          // half-wave id 0..7
    const int j     = tid & 31;
    const int bx    = blockIdx.x;
    const int chunk = bx & (NCHUNK - 1); // consecutive bx -> consecutive chunk,
    const int bg    = bx >> 7;           // same-chunk blocks land on same XCD (mod 8)
    const int b     = bg * BB + hw;

    // Vacc[b][j][:] is invariant over the i-loop -> registers, once.
    float vacc[E_DIM];
    {
        const float4* vp = (const float4*)(Vacc + ((size_t)(b * J_DIM + j)) * E_DIM);
        float4 t0 = vp[0], t1 = vp[1], t2 = vp[2], t3 = vp[3];
        vacc[0]=t0.x; vacc[1]=t0.y; vacc[2]=t0.z;  vacc[3]=t0.w;
        vacc[4]=t1.x; vacc[5]=t1.y; vacc[6]=t1.z;  vacc[7]=t1.w;
        vacc[8]=t2.x; vacc[9]=t2.y; vacc[10]=t2.z; vacc[11]=t2.w;
        vacc[12]=t3.x; vacc[13]=t3.y; vacc[14]=t3.z; vacc[15]=t3.w;
    }

    float Sacc[E_DIM];
    #pragma unroll
    for (int e = 0; e < E_DIM; ++e) Sacc[e] = 0.f;

    const int i0 = chunk * CHUNK;
    for (int ii = 0; ii < CHUNK; ++ii) {
        const int i = i0 + ii;

        // x[b][i][0:8] (same 32B for all 32 lanes of the half-wave -> broadcast)
        const float* xp = x + ((size_t)b * I_DIM + i) * D_IN;
        const float4 xa = *(const float4*)xp;
        const float4 xb = *(const float4*)(xp + 4);
        const float xd[8] = {xa.x, xa.y, xa.z, xa.w, xb.x, xb.y, xb.z, xb.w};

        // u_hat[j][e] = sum_d x[d] * W[i][j][d][e]
        float uh[E_DIM];
        #pragma unroll
        for (int e = 0; e < E_DIM; ++e) uh[e] = 0.f;

        const float* wp = W + ((size_t)i * J_DIM + j) * (D_IN * E_DIM);
        #pragma unroll
        for (int d = 0; d < D_IN; ++d) {
            const float4 w0 = *(const float4*)(wp + d * E_DIM + 0);
            const float4 w1 = *(const float4*)(wp + d * E_DIM + 4);
            const float4 w2 = *(const float4*)(wp + d * E_DIM + 8);
            const float4 w3 = *(const float4*)(wp + d * E_DIM + 12);
            const float xv = xd[d];
            uh[0]  = fmaf(xv, w0.x, uh[0]);
            uh[1]  = fmaf(xv, w0.y, uh[1]);
            uh[2]  = fmaf(xv, w0.z, uh[2]);
            uh[3]  = fmaf(xv, w0.w, uh[3]);
            uh[4]  = fmaf(xv, w1.x, uh[4]);
            uh[5]  = fmaf(xv, w1.y, uh[5]);
            uh[6]  = fmaf(xv, w1.z, uh[6]);
            uh[7]  = fmaf(xv, w1.w, uh[7]);
            uh[8]  = fmaf(xv, w2.x, uh[8]);
            uh[9]  = fmaf(xv, w2.y, uh[9]);
            uh[10] = fmaf(xv, w2.z, uh[10]);
            uh[11] = fmaf(xv, w2.w, uh[11]);
            uh[12] = fmaf(xv, w3.x, uh[12]);
            uh[13] = fmaf(xv, w3.y, uh[13]);
            uh[14] = fmaf(xv, w3.z, uh[14]);
            uh[15] = fmaf(xv, w3.w, uh[15]);
        }

        // logit[b,i,j] = b0[i,j] + Vacc[b,j,:] . u_hat[j,:]   (lane-local)
        float l = b0[i * J_DIM + j];
        #pragma unroll
        for (int e = 0; e < E_DIM; ++e) l = fmaf(vacc[e], uh[e], l);

        // softmax over j (32 lanes of the half-wave; xor masks <=16 stay in-half)
        float m = l;
        #pragma unroll
        for (int k = 16; k >= 1; k >>= 1) m = fmaxf(m, __shfl_xor(m, k));
        const float p = __expf(l - m);
        float s = p;
        #pragma unroll
        for (int k = 16; k >= 1; k >>= 1) s += __shfl_xor(s, k);
        const float c = p / s;

        #pragma unroll
        for (int e = 0; e < E_DIM; ++e) Sacc[e] = fmaf(c, uh[e], Sacc[e]);
    }

    float* sp = S + ((size_t)(b * J_DIM + j)) * E_DIM;
    #pragma unroll
    for (int e = 0; e < E_DIM; ++e) atomicAdd(sp + e, Sacc[e]);
}

// V = squash(S); Vacc += V (non-final) or out = V (final). tid over B*J*E.
__global__ __launch_bounds__(256) void squash_k(
    const float* __restrict__ S, float* __restrict__ Vacc,
    float* __restrict__ out, const int final_it)
{
    const int tid = blockIdx.x * blockDim.x + threadIdx.x;
    const float sv = S[tid];
    float s2 = sv * sv;
    #pragma unroll
    for (int k = 8; k >= 1; k >>= 1) s2 += __shfl_xor(s2, k);  // reduce over e (16 lanes)
    const float scale = s2 / (1.f + s2) * rsqrtf(s2 + 1e-7f);
    const float v = scale * sv;
    if (final_it) out[tid] = v;
    else Vacc[tid] += v;
}

extern "C" void kernel_launch(void* const* d_in, const int* in_sizes, int n_in,
                              void* d_out, int out_size, void* d_ws, size_t ws_size,
                              hipStream_t stream) {
    const float* x  = (const float*)d_in[0];   // [64,2304,8]
    const float* W  = (const float*)d_in[1];   // [2304,32,8,16]
    const float* b0 = (const float*)d_in[2];   // [2304,32]
    float* out  = (float*)d_out;               // [64,32,16]

    const int SJE = B_DIM * J_DIM * E_DIM;     // 32768
    float* S    = (float*)d_ws;                // 128 KB
    float* Vacc = S + SJE;                     // 128 KB

    hipMemsetAsync(Vacc, 0, SJE * sizeof(float), stream);

    const int grid = (B_DIM / BB) * NCHUNK;    // 8 * 128 = 1024 blocks
    for (int it = 0; it < 3; ++it) {
        hipMemsetAsync(S, 0, SJE * sizeof(float), stream);
        caps_pass<<<grid, 256, 0, stream>>>(x, W, b0, Vacc, S);
        squash_k<<<SJE / 256, 256, 0, stream>>>(S, Vacc, out, it == 2 ? 1 : 0);
    }
}

// Round 3
// 1036.476 us; speedup vs baseline: 1.3798x; 1.3798x over previous
//
#include <hip/hip_runtime.h>

#define I_DIM 2304
#define J_DIM 32
#define D_IN  8
#define E_DIM 16
#define B_DIM 64
#define BB    8                        // b's per block (8 half-waves)
#define BJE   (B_DIM * J_DIM * E_DIM)  // 32768

// One half-wave (32 lanes) owns one (b, i): lane = j.
// Lane holds u_hat[j][0:16] in regs; softmax over j = shfl over 32 lanes.
// Each block writes its partial S to partial[chunk][b][j][e] — NO atomics.
template <int NC>
__global__ __launch_bounds__(256, 8) void caps_pass_p(
    const float* __restrict__ x,    // [B, I, 8]
    const float* __restrict__ W,    // [I, J, 8, 16]
    const float* __restrict__ b0,   // [I, J]
    const float* __restrict__ Vacc, // [B, J, 16]
    float* __restrict__ partial)    // [NC, B, J, 16]
{
    const int CH    = I_DIM / NC;
    const int tid   = threadIdx.x;
    const int hw    = tid >> 5;
    const int j     = tid & 31;
    const int bx    = blockIdx.x;
    const int chunk = bx & (NC - 1);   // consecutive bx -> same-chunk on same XCD
    const int bg    = bx / NC;
    const int b     = bg * BB + hw;

    float vacc[E_DIM];
    {
        const float4* vp = (const float4*)(Vacc + ((size_t)(b * J_DIM + j)) * E_DIM);
        float4 t0 = vp[0], t1 = vp[1], t2 = vp[2], t3 = vp[3];
        vacc[0]=t0.x; vacc[1]=t0.y; vacc[2]=t0.z;  vacc[3]=t0.w;
        vacc[4]=t1.x; vacc[5]=t1.y; vacc[6]=t1.z;  vacc[7]=t1.w;
        vacc[8]=t2.x; vacc[9]=t2.y; vacc[10]=t2.z; vacc[11]=t2.w;
        vacc[12]=t3.x; vacc[13]=t3.y; vacc[14]=t3.z; vacc[15]=t3.w;
    }

    float Sacc[E_DIM];
    #pragma unroll
    for (int e = 0; e < E_DIM; ++e) Sacc[e] = 0.f;

    const int i0 = chunk * CH;
    for (int ii = 0; ii < CH; ++ii) {
        const int i = i0 + ii;

        const float* xp = x + ((size_t)b * I_DIM + i) * D_IN;
        const float4 xa = *(const float4*)xp;
        const float4 xb = *(const float4*)(xp + 4);
        const float xd[8] = {xa.x, xa.y, xa.z, xa.w, xb.x, xb.y, xb.z, xb.w};

        float uh[E_DIM];
        #pragma unroll
        for (int e = 0; e < E_DIM; ++e) uh[e] = 0.f;

        const float* wp = W + ((size_t)i * J_DIM + j) * (D_IN * E_DIM);
        #pragma unroll
        for (int d = 0; d < D_IN; ++d) {
            const float4 w0 = *(const float4*)(wp + d * E_DIM + 0);
            const float4 w1 = *(const float4*)(wp + d * E_DIM + 4);
            const float4 w2 = *(const float4*)(wp + d * E_DIM + 8);
            const float4 w3 = *(const float4*)(wp + d * E_DIM + 12);
            const float xv = xd[d];
            uh[0]  = fmaf(xv, w0.x, uh[0]);
            uh[1]  = fmaf(xv, w0.y, uh[1]);
            uh[2]  = fmaf(xv, w0.z, uh[2]);
            uh[3]  = fmaf(xv, w0.w, uh[3]);
            uh[4]  = fmaf(xv, w1.x, uh[4]);
            uh[5]  = fmaf(xv, w1.y, uh[5]);
            uh[6]  = fmaf(xv, w1.z, uh[6]);
            uh[7]  = fmaf(xv, w1.w, uh[7]);
            uh[8]  = fmaf(xv, w2.x, uh[8]);
            uh[9]  = fmaf(xv, w2.y, uh[9]);
            uh[10] = fmaf(xv, w2.z, uh[10]);
            uh[11] = fmaf(xv, w2.w, uh[11]);
            uh[12] = fmaf(xv, w3.x, uh[12]);
            uh[13] = fmaf(xv, w3.y, uh[13]);
            uh[14] = fmaf(xv, w3.z, uh[14]);
            uh[15] = fmaf(xv, w3.w, uh[15]);
        }

        float l = b0[i * J_DIM + j];
        #pragma unroll
        for (int e = 0; e < E_DIM; ++e) l = fmaf(vacc[e], uh[e], l);

        float m = l;
        #pragma unroll
        for (int k = 16; k >= 1; k >>= 1) m = fmaxf(m, __shfl_xor(m, k));
        const float p = __expf(l - m);
        float s = p;
        #pragma unroll
        for (int k = 16; k >= 1; k >>= 1) s += __shfl_xor(s, k);
        const float c = p / s;

        #pragma unroll
        for (int e = 0; e < E_DIM; ++e) Sacc[e] = fmaf(c, uh[e], Sacc[e]);
    }

    float* pp = partial + ((size_t)chunk * BJE) + ((size_t)(b * J_DIM + j)) * E_DIM;
    float4* pv = (float4*)pp;
    pv[0] = make_float4(Sacc[0],  Sacc[1],  Sacc[2],  Sacc[3]);
    pv[1] = make_float4(Sacc[4],  Sacc[5],  Sacc[6],  Sacc[7]);
    pv[2] = make_float4(Sacc[8],  Sacc[9],  Sacc[10], Sacc[11]);
    pv[3] = make_float4(Sacc[12], Sacc[13], Sacc[14], Sacc[15]);
}

// Sum partials over chunks, then squash. t indexes (b,j,e); e = t&15.
__global__ __launch_bounds__(256) void reduce_squash(
    const float* __restrict__ partial, float* __restrict__ Vacc,
    float* __restrict__ out, const int nc, const int final_it)
{
    const int t = blockIdx.x * blockDim.x + threadIdx.x;  // 0..BJE-1
    float acc = 0.f;
    for (int c = 0; c < nc; ++c) acc += partial[(size_t)c * BJE + t];  // coalesced

    float s2 = acc * acc;
    #pragma unroll
    for (int k = 8; k >= 1; k >>= 1) s2 += __shfl_xor(s2, k);  // reduce over e
    const float scale = s2 / (1.f + s2) * rsqrtf(s2 + 1e-7f);
    const float v = scale * acc;
    if (final_it) out[t] = v;
    else Vacc[t] += v;
}

// ---------------- fallback (tiny ws): original atomic version ----------------
__global__ __launch_bounds__(256) void caps_pass_atomic(
    const float* __restrict__ x, const float* __restrict__ W,
    const float* __restrict__ b0, const float* __restrict__ Vacc,
    float* __restrict__ S)
{
    const int NC = 128, CH = I_DIM / NC;
    const int tid = threadIdx.x, hw = tid >> 5, j = tid & 31;
    const int chunk = blockIdx.x & (NC - 1), bg = blockIdx.x >> 7;
    const int b = bg * BB + hw;

    float vacc[E_DIM];
    const float* vp = Vacc + ((size_t)(b * J_DIM + j)) * E_DIM;
    #pragma unroll
    for (int e = 0; e < E_DIM; ++e) vacc[e] = vp[e];

    float Sacc[E_DIM];
    #pragma unroll
    for (int e = 0; e < E_DIM; ++e) Sacc[e] = 0.f;

    const int i0 = chunk * CH;
    for (int ii = 0; ii < CH; ++ii) {
        const int i = i0 + ii;
        const float* xp = x + ((size_t)b * I_DIM + i) * D_IN;
        float xd[8];
        #pragma unroll
        for (int d = 0; d < D_IN; ++d) xd[d] = xp[d];
        float uh[E_DIM];
        #pragma unroll
        for (int e = 0; e < E_DIM; ++e) uh[e] = 0.f;
        const float* wp = W + ((size_t)i * J_DIM + j) * (D_IN * E_DIM);
        #pragma unroll
        for (int d = 0; d < D_IN; ++d)
            #pragma unroll
            for (int e = 0; e < E_DIM; ++e) uh[e] = fmaf(xd[d], wp[d * E_DIM + e], uh[e]);
        float l = b0[i * J_DIM + j];
        #pragma unroll
        for (int e = 0; e < E_DIM; ++e) l = fmaf(vacc[e], uh[e], l);
        float m = l;
        #pragma unroll
        for (int k = 16; k >= 1; k >>= 1) m = fmaxf(m, __shfl_xor(m, k));
        const float p = __expf(l - m);
        float s = p;
        #pragma unroll
        for (int k = 16; k >= 1; k >>= 1) s += __shfl_xor(s, k);
        const float c = p / s;
        #pragma unroll
        for (int e = 0; e < E_DIM; ++e) Sacc[e] = fmaf(c, uh[e], Sacc[e]);
    }
    float* sp = S + ((size_t)(b * J_DIM + j)) * E_DIM;
    #pragma unroll
    for (int e = 0; e < E_DIM; ++e) atomicAdd(sp + e, Sacc[e]);
}

__global__ __launch_bounds__(256) void squash_k(
    const float* __restrict__ S, float* __restrict__ Vacc,
    float* __restrict__ out, const int final_it)
{
    const int tid = blockIdx.x * blockDim.x + threadIdx.x;
    const float sv = S[tid];
    float s2 = sv * sv;
    #pragma unroll
    for (int k = 8; k >= 1; k >>= 1) s2 += __shfl_xor(s2, k);
    const float scale = s2 / (1.f + s2) * rsqrtf(s2 + 1e-7f);
    const float v = scale * sv;
    if (final_it) out[tid] = v;
    else Vacc[tid] += v;
}

extern "C" void kernel_launch(void* const* d_in, const int* in_sizes, int n_in,
                              void* d_out, int out_size, void* d_ws, size_t ws_size,
                              hipStream_t stream) {
    const float* x  = (const float*)d_in[0];   // [64,2304,8]
    const float* W  = (const float*)d_in[1];   // [2304,32,8,16]
    const float* b0 = (const float*)d_in[2];   // [2304,32]
    float* out = (float*)d_out;                // [64,32,16]

    const size_t need256 = ((size_t)256 * BJE + BJE) * sizeof(float);  // 33.7 MB
    const size_t need128 = ((size_t)128 * BJE + BJE) * sizeof(float);  // 16.9 MB

    if (ws_size >= need256 || ws_size >= need128) {
        const int NC = (ws_size >= need256) ? 256 : 128;
        float* partial = (float*)d_ws;
        float* Vacc    = partial + (size_t)NC * BJE;
        hipMemsetAsync(Vacc, 0, BJE * sizeof(float), stream);
        const int grid = (B_DIM / BB) * NC;
        for (int it = 0; it < 3; ++it) {
            if (NC == 256)
                caps_pass_p<256><<<grid, 256, 0, stream>>>(x, W, b0, Vacc, partial);
            else
                caps_pass_p<128><<<grid, 256, 0, stream>>>(x, W, b0, Vacc, partial);
            reduce_squash<<<BJE / 256, 256, 0, stream>>>(partial, Vacc, out, NC, it == 2 ? 1 : 0);
        }
    } else {
        float* S    = (float*)d_ws;
        float* Vacc = S + BJE;
        hipMemsetAsync(Vacc, 0, BJE * sizeof(float), stream);
        for (int it = 0; it < 3; ++it) {
            hipMemsetAsync(S, 0, BJE * sizeof(float), stream);
            caps_pass_atomic<<<1024, 256, 0, stream>>>(x, W, b0, Vacc, S);
            squash_k<<<BJE / 256, 256, 0, stream>>>(S, Vacc, out, it == 2 ? 1 : 0);
        }
    }
}

// Round 4
// 351.553 us; speedup vs baseline: 4.0682x; 2.9483x over previous
//
#include <hip/hip_runtime.h>

#define I_DIM 2304
#define J_DIM 32
#define D_IN  8
#define E_DIM 16
#define B_DIM 64
#define BB    8                        // b's per block (8 half-waves)
#define BJE   (B_DIM * J_DIM * E_DIM)  // 32768
#define ROWF  132                      // 128 data floats + 4 pad (breaks 512B-stride banks)
#define TILEF (J_DIM * ROWF)           // 4224 floats = 16.9 KB per buffer

// One half-wave (32 lanes) owns one (b, i): lane = j. All 8 half-waves of a
// block share the same i-sequence -> W[i] staged once in LDS per iteration.
// Pipeline: ds_write(tile ii) ; barrier ; prefetch(ii+1)->regs ; compute(ii).
// Prefetch is consumed by next iter's ds_write with no barrier in between, so
// global latency hides under compute.
template <int NC>
__global__ __launch_bounds__(256, 4) void caps_pass_lds(
    const float* __restrict__ x,    // [B, I, 8]
    const float* __restrict__ W,    // [I, J, 8, 16]
    const float* __restrict__ b0,   // [I, J]
    const float* __restrict__ Vacc, // [B, J, 16]
    float* __restrict__ partial)    // [NC, B, J, 16]
{
    constexpr int CH = I_DIM / NC;
    const int tid   = threadIdx.x;
    const int hw    = tid >> 5;
    const int j     = tid & 31;
    const int bx    = blockIdx.x;
    const int chunk = bx & (NC - 1);   // same chunk -> same XCD (grid mult of 8)
    const int bg    = bx / NC;
    const int b     = bg * BB + hw;

    __shared__ float Ws[2][TILEF];

    // staging map: thread handles 16B-groups g = r*256+tid; row = g>>5, slot = g&31
    int dstf[4];
    #pragma unroll
    for (int r = 0; r < 4; ++r) {
        const int g = r * 256 + tid;
        dstf[r] = (g >> 5) * ROWF + (g & 31) * 4;
    }

    const int i0 = chunk * CH;

    // prologue prefetch of tile i0
    float4 stg[4];
    {
        const float4* src = (const float4*)(W + (size_t)i0 * (J_DIM * D_IN * E_DIM));
        #pragma unroll
        for (int r = 0; r < 4; ++r) stg[r] = src[r * 256 + tid];
    }

    float vacc[E_DIM];
    {
        const float4* vp = (const float4*)(Vacc + ((size_t)(b * J_DIM + j)) * E_DIM);
        float4 t0 = vp[0], t1 = vp[1], t2 = vp[2], t3 = vp[3];
        vacc[0]=t0.x; vacc[1]=t0.y; vacc[2]=t0.z;  vacc[3]=t0.w;
        vacc[4]=t1.x; vacc[5]=t1.y; vacc[6]=t1.z;  vacc[7]=t1.w;
        vacc[8]=t2.x; vacc[9]=t2.y; vacc[10]=t2.z; vacc[11]=t2.w;
        vacc[12]=t3.x; vacc[13]=t3.y; vacc[14]=t3.z; vacc[15]=t3.w;
    }

    float Sacc[E_DIM];
    #pragma unroll
    for (int e = 0; e < E_DIM; ++e) Sacc[e] = 0.f;

    for (int ii = 0; ii < CH; ++ii) {
        const int cb = ii & 1;
        float* wbuf = &Ws[cb][0];

        // A: commit prefetched tile to LDS (compiler inserts vmcnt wait on stg)
        #pragma unroll
        for (int r = 0; r < 4; ++r) *(float4*)&wbuf[dstf[r]] = stg[r];

        __syncthreads();  // B: tile visible; prev readers of other buffer done

        // C: prefetch next tile (in flight across compute, no barrier until used)
        if (ii + 1 < CH) {
            const float4* src = (const float4*)(W + (size_t)(i0 + ii + 1) * (J_DIM * D_IN * E_DIM));
            #pragma unroll
            for (int r = 0; r < 4; ++r) stg[r] = src[r * 256 + tid];
        }

        // D: compute from LDS
        const int i = i0 + ii;
        const float* xp = x + ((size_t)b * I_DIM + i) * D_IN;
        const float4 xa = *(const float4*)xp;
        const float4 xb = *(const float4*)(xp + 4);
        const float xd[8] = {xa.x, xa.y, xa.z, xa.w, xb.x, xb.y, xb.z, xb.w};

        float uh[E_DIM];
        #pragma unroll
        for (int e = 0; e < E_DIM; ++e) uh[e] = 0.f;

        const float* wr = &wbuf[j * ROWF];
        #pragma unroll
        for (int d = 0; d < D_IN; ++d) {
            const float4 w0 = *(const float4*)(wr + d * 16 + 0);
            const float4 w1 = *(const float4*)(wr + d * 16 + 4);
            const float4 w2 = *(const float4*)(wr + d * 16 + 8);
            const float4 w3 = *(const float4*)(wr + d * 16 + 12);
            const float xv = xd[d];
            uh[0]  = fmaf(xv, w0.x, uh[0]);
            uh[1]  = fmaf(xv, w0.y, uh[1]);
            uh[2]  = fmaf(xv, w0.z, uh[2]);
            uh[3]  = fmaf(xv, w0.w, uh[3]);
            uh[4]  = fmaf(xv, w1.x, uh[4]);
            uh[5]  = fmaf(xv, w1.y, uh[5]);
            uh[6]  = fmaf(xv, w1.z, uh[6]);
            uh[7]  = fmaf(xv, w1.w, uh[7]);
            uh[8]  = fmaf(xv, w2.x, uh[8]);
            uh[9]  = fmaf(xv, w2.y, uh[9]);
            uh[10] = fmaf(xv, w2.z, uh[10]);
            uh[11] = fmaf(xv, w2.w, uh[11]);
            uh[12] = fmaf(xv, w3.x, uh[12]);
            uh[13] = fmaf(xv, w3.y, uh[13]);
            uh[14] = fmaf(xv, w3.z, uh[14]);
            uh[15] = fmaf(xv, w3.w, uh[15]);
        }

        float l = b0[i * J_DIM + j];
        #pragma unroll
        for (int e = 0; e < E_DIM; ++e) l = fmaf(vacc[e], uh[e], l);

        float m = l;
        #pragma unroll
        for (int k = 16; k >= 1; k >>= 1) m = fmaxf(m, __shfl_xor(m, k));
        const float p = __expf(l - m);
        float s = p;
        #pragma unroll
        for (int k = 16; k >= 1; k >>= 1) s += __shfl_xor(s, k);
        const float c = p / s;

        #pragma unroll
        for (int e = 0; e < E_DIM; ++e) Sacc[e] = fmaf(c, uh[e], Sacc[e]);
    }

    float* pp = partial + ((size_t)chunk * BJE) + ((size_t)(b * J_DIM + j)) * E_DIM;
    float4* pv = (float4*)pp;
    pv[0] = make_float4(Sacc[0],  Sacc[1],  Sacc[2],  Sacc[3]);
    pv[1] = make_float4(Sacc[4],  Sacc[5],  Sacc[6],  Sacc[7]);
    pv[2] = make_float4(Sacc[8],  Sacc[9],  Sacc[10], Sacc[11]);
    pv[3] = make_float4(Sacc[12], Sacc[13], Sacc[14], Sacc[15]);
}

// Sum partials over chunks (8 independent accumulators for MLP latency), squash.
__global__ __launch_bounds__(256) void reduce_squash(
    const float* __restrict__ partial, float* __restrict__ Vacc,
    float* __restrict__ out, const int nc, const int final_it)
{
    const int t = blockIdx.x * blockDim.x + threadIdx.x;  // 0..BJE-1
    float a0=0.f,a1=0.f,a2=0.f,a3=0.f,a4=0.f,a5=0.f,a6=0.f,a7=0.f;
    for (int c = 0; c < nc; c += 8) {
        a0 += partial[(size_t)(c+0) * BJE + t];
        a1 += partial[(size_t)(c+1) * BJE + t];
        a2 += partial[(size_t)(c+2) * BJE + t];
        a3 += partial[(size_t)(c+3) * BJE + t];
        a4 += partial[(size_t)(c+4) * BJE + t];
        a5 += partial[(size_t)(c+5) * BJE + t];
        a6 += partial[(size_t)(c+6) * BJE + t];
        a7 += partial[(size_t)(c+7) * BJE + t];
    }
    const float acc = ((a0+a1)+(a2+a3)) + ((a4+a5)+(a6+a7));

    float s2 = acc * acc;
    #pragma unroll
    for (int k = 8; k >= 1; k >>= 1) s2 += __shfl_xor(s2, k);  // reduce over e
    const float scale = s2 / (1.f + s2) * rsqrtf(s2 + 1e-7f);
    const float v = scale * acc;
    if (final_it) out[t] = v;
    else Vacc[t] += v;
}

// ---------------- fallback (tiny ws): atomic version ----------------
__global__ __launch_bounds__(256) void caps_pass_atomic(
    const float* __restrict__ x, const float* __restrict__ W,
    const float* __restrict__ b0, const float* __restrict__ Vacc,
    float* __restrict__ S)
{
    const int NC = 128, CH = I_DIM / NC;
    const int tid = threadIdx.x, hw = tid >> 5, j = tid & 31;
    const int chunk = blockIdx.x & (NC - 1), bg = blockIdx.x >> 7;
    const int b = bg * BB + hw;

    float vacc[E_DIM];
    const float* vp = Vacc + ((size_t)(b * J_DIM + j)) * E_DIM;
    #pragma unroll
    for (int e = 0; e < E_DIM; ++e) vacc[e] = vp[e];

    float Sacc[E_DIM];
    #pragma unroll
    for (int e = 0; e < E_DIM; ++e) Sacc[e] = 0.f;

    const int i0 = chunk * CH;
    for (int ii = 0; ii < CH; ++ii) {
        const int i = i0 + ii;
        const float* xp = x + ((size_t)b * I_DIM + i) * D_IN;
        float xd[8];
        #pragma unroll
        for (int d = 0; d < D_IN; ++d) xd[d] = xp[d];
        float uh[E_DIM];
        #pragma unroll
        for (int e = 0; e < E_DIM; ++e) uh[e] = 0.f;
        const float* wp = W + ((size_t)i * J_DIM + j) * (D_IN * E_DIM);
        #pragma unroll
        for (int d = 0; d < D_IN; ++d)
            #pragma unroll
            for (int e = 0; e < E_DIM; ++e) uh[e] = fmaf(xd[d], wp[d * E_DIM + e], uh[e]);
        float l = b0[i * J_DIM + j];
        #pragma unroll
        for (int e = 0; e < E_DIM; ++e) l = fmaf(vacc[e], uh[e], l);
        float m = l;
        #pragma unroll
        for (int k = 16; k >= 1; k >>= 1) m = fmaxf(m, __shfl_xor(m, k));
        const float p = __expf(l - m);
        float s = p;
        #pragma unroll
        for (int k = 16; k >= 1; k >>= 1) s += __shfl_xor(s, k);
        const float c = p / s;
        #pragma unroll
        for (int e = 0; e < E_DIM; ++e) Sacc[e] = fmaf(c, uh[e], Sacc[e]);
    }
    float* sp = S + ((size_t)(b * J_DIM + j)) * E_DIM;
    #pragma unroll
    for (int e = 0; e < E_DIM; ++e) atomicAdd(sp + e, Sacc[e]);
}

__global__ __launch_bounds__(256) void squash_k(
    const float* __restrict__ S, float* __restrict__ Vacc,
    float* __restrict__ out, const int final_it)
{
    const int tid = blockIdx.x * blockDim.x + threadIdx.x;
    const float sv = S[tid];
    float s2 = sv * sv;
    #pragma unroll
    for (int k = 8; k >= 1; k >>= 1) s2 += __shfl_xor(s2, k);
    const float scale = s2 / (1.f + s2) * rsqrtf(s2 + 1e-7f);
    const float v = scale * sv;
    if (final_it) out[tid] = v;
    else Vacc[tid] += v;
}

extern "C" void kernel_launch(void* const* d_in, const int* in_sizes, int n_in,
                              void* d_out, int out_size, void* d_ws, size_t ws_size,
                              hipStream_t stream) {
    const float* x  = (const float*)d_in[0];   // [64,2304,8]
    const float* W  = (const float*)d_in[1];   // [2304,32,8,16]
    const float* b0 = (const float*)d_in[2];   // [2304,32]
    float* out = (float*)d_out;                // [64,32,16]

    const size_t need256 = ((size_t)256 * BJE + BJE) * sizeof(float);  // 33.7 MB
    const size_t need128 = ((size_t)128 * BJE + BJE) * sizeof(float);  // 16.9 MB

    if (ws_size >= need128) {
        const int NC = (ws_size >= need256) ? 256 : 128;
        float* partial = (float*)d_ws;
        float* Vacc    = partial + (size_t)NC * BJE;
        hipMemsetAsync(Vacc, 0, BJE * sizeof(float), stream);
        const int grid = (B_DIM / BB) * NC;
        for (int it = 0; it < 3; ++it) {
            if (NC == 256)
                caps_pass_lds<256><<<grid, 256, 0, stream>>>(x, W, b0, Vacc, partial);
            else
                caps_pass_lds<128><<<grid, 256, 0, stream>>>(x, W, b0, Vacc, partial);
            reduce_squash<<<BJE / 256, 256, 0, stream>>>(partial, Vacc, out, NC, it == 2 ? 1 : 0);
        }
    } else {
        float* S    = (float*)d_ws;
        float* Vacc = S + BJE;
        hipMemsetAsync(Vacc, 0, BJE * sizeof(float), stream);
        for (int it = 0; it < 3; ++it) {
            hipMemsetAsync(S, 0, BJE * sizeof(float), stream);
            caps_pass_atomic<<<1024, 256, 0, stream>>>(x, W, b0, Vacc, S);
            squash_k<<<BJE / 256, 256, 0, stream>>>(S, Vacc, out, it == 2 ? 1 : 0);
        }
    }
}

// Round 5
// 230.725 us; speedup vs baseline: 6.1986x; 1.5237x over previous
//
#include <hip/hip_runtime.h>

#define I_DIM 2304
#define J_DIM 32
#define D_IN  8
#define E_DIM 16
#define B_DIM 64
#define BJE   (B_DIM * J_DIM * E_DIM)  // 32768
#define ROWF  132                      // 128 data floats + 4 pad
#define TILEF (J_DIM * ROWF)           // 4224 floats
#define WTILE (J_DIM * D_IN * E_DIM)   // 4096 floats = 16 KB
#define NC5   256
#define CH5   (I_DIM / NC5)            // 9

// grid = 256 (one block per i-chunk), 512 threads = 16 half-waves.
// Half-wave hw (lane=j) handles b = hw*4 + bb, bb<4. W tile staged to LDS once
// per i and each W row is read ONCE per lane and applied to 4 b's in registers.
__global__ __launch_bounds__(512, 2) void caps_pass_v5(
    const float* __restrict__ x,    // [B, I, 8]
    const float* __restrict__ W,    // [I, J, 8, 16]
    const float* __restrict__ b0,   // [I, J]
    const float* __restrict__ Vacc, // [B, J, 16]
    float* __restrict__ partial)    // [NC5, B, J, 16]
{
    const int tid   = threadIdx.x;
    const int hw    = tid >> 5;      // 0..15
    const int j     = tid & 31;
    const int chunk = blockIdx.x;    // 0..255
    const int i0    = chunk * CH5;
    const int bbase = hw * 4;

    __shared__ float Ws[2][TILEF];
    __shared__ float Xs[2][B_DIM * D_IN];  // 512 floats

    // W staging map: 1024 16B-groups; thread handles g = r*512+tid
    int dstf[2];
#pragma unroll
    for (int r = 0; r < 2; ++r) {
        const int g = r * 512 + tid;
        dstf[r] = (g >> 5) * ROWF + (g & 31) * 4;
    }
    // x staging: thread t loads element (b = t>>3, d = t&7)
    const int xb = tid >> 3, xdi = tid & 7;

    // prologue prefetch of tile i0
    float4 stgW[2];
    float  stgX;
    {
        const float4* src = (const float4*)(W + (size_t)i0 * WTILE);
#pragma unroll
        for (int r = 0; r < 2; ++r) stgW[r] = src[r * 512 + tid];
        stgX = x[((size_t)xb * I_DIM + i0) * D_IN + xdi];
    }

    float vacc[4][E_DIM];
#pragma unroll
    for (int bb = 0; bb < 4; ++bb) {
        const float4* vp = (const float4*)(Vacc + ((size_t)((bbase + bb) * J_DIM + j)) * E_DIM);
        float4 t0 = vp[0], t1 = vp[1], t2 = vp[2], t3 = vp[3];
        vacc[bb][0]=t0.x;  vacc[bb][1]=t0.y;  vacc[bb][2]=t0.z;  vacc[bb][3]=t0.w;
        vacc[bb][4]=t1.x;  vacc[bb][5]=t1.y;  vacc[bb][6]=t1.z;  vacc[bb][7]=t1.w;
        vacc[bb][8]=t2.x;  vacc[bb][9]=t2.y;  vacc[bb][10]=t2.z; vacc[bb][11]=t2.w;
        vacc[bb][12]=t3.x; vacc[bb][13]=t3.y; vacc[bb][14]=t3.z; vacc[bb][15]=t3.w;
    }

    float Sacc[4][E_DIM];
#pragma unroll
    for (int bb = 0; bb < 4; ++bb)
#pragma unroll
        for (int e = 0; e < E_DIM; ++e) Sacc[bb][e] = 0.f;

    for (int ii = 0; ii < CH5; ++ii) {
        float* wbuf = &Ws[ii & 1][0];
        float* xbuf = &Xs[ii & 1][0];

        // commit prefetched tile (compiler inserts vmcnt wait)
#pragma unroll
        for (int r = 0; r < 2; ++r) *(float4*)&wbuf[dstf[r]] = stgW[r];
        xbuf[tid] = stgX;

        __syncthreads();

        // prefetch next tile — stays in flight across compute
        if (ii + 1 < CH5) {
            const float4* src = (const float4*)(W + (size_t)(i0 + ii + 1) * WTILE);
#pragma unroll
            for (int r = 0; r < 2; ++r) stgW[r] = src[r * 512 + tid];
            stgX = x[((size_t)xb * I_DIM + (i0 + ii + 1)) * D_IN + xdi];
        }

        const int i = i0 + ii;

        float uh[4][E_DIM];
#pragma unroll
        for (int bb = 0; bb < 4; ++bb)
#pragma unroll
            for (int e = 0; e < E_DIM; ++e) uh[bb][e] = 0.f;

        const float* wr = &wbuf[j * ROWF];
#pragma unroll
        for (int d = 0; d < D_IN; ++d) {
            const float4 w0 = *(const float4*)(wr + d * 16 + 0);
            const float4 w1 = *(const float4*)(wr + d * 16 + 4);
            const float4 w2 = *(const float4*)(wr + d * 16 + 8);
            const float4 w3 = *(const float4*)(wr + d * 16 + 12);
            float xv[4];
#pragma unroll
            for (int bb = 0; bb < 4; ++bb) xv[bb] = xbuf[(bbase + bb) * D_IN + d];
#pragma unroll
            for (int bb = 0; bb < 4; ++bb) {
                const float xvb = xv[bb];
                uh[bb][0]  = fmaf(xvb, w0.x, uh[bb][0]);
                uh[bb][1]  = fmaf(xvb, w0.y, uh[bb][1]);
                uh[bb][2]  = fmaf(xvb, w0.z, uh[bb][2]);
                uh[bb][3]  = fmaf(xvb, w0.w, uh[bb][3]);
                uh[bb][4]  = fmaf(xvb, w1.x, uh[bb][4]);
                uh[bb][5]  = fmaf(xvb, w1.y, uh[bb][5]);
                uh[bb][6]  = fmaf(xvb, w1.z, uh[bb][6]);
                uh[bb][7]  = fmaf(xvb, w1.w, uh[bb][7]);
                uh[bb][8]  = fmaf(xvb, w2.x, uh[bb][8]);
                uh[bb][9]  = fmaf(xvb, w2.y, uh[bb][9]);
                uh[bb][10] = fmaf(xvb, w2.z, uh[bb][10]);
                uh[bb][11] = fmaf(xvb, w2.w, uh[bb][11]);
                uh[bb][12] = fmaf(xvb, w3.x, uh[bb][12]);
                uh[bb][13] = fmaf(xvb, w3.y, uh[bb][13]);
                uh[bb][14] = fmaf(xvb, w3.z, uh[bb][14]);
                uh[bb][15] = fmaf(xvb, w3.w, uh[bb][15]);
            }
        }

        const float b0v = b0[i * J_DIM + j];
#pragma unroll
        for (int bb = 0; bb < 4; ++bb) {
            float l0 = 0.f, l1 = 0.f, l2 = 0.f, l3 = 0.f;
#pragma unroll
            for (int e = 0; e < E_DIM; e += 4) {
                l0 = fmaf(vacc[bb][e+0], uh[bb][e+0], l0);
                l1 = fmaf(vacc[bb][e+1], uh[bb][e+1], l1);
                l2 = fmaf(vacc[bb][e+2], uh[bb][e+2], l2);
                l3 = fmaf(vacc[bb][e+3], uh[bb][e+3], l3);
            }
            const float l = b0v + ((l0 + l1) + (l2 + l3));

            float m = l;
#pragma unroll
            for (int k = 16; k >= 1; k >>= 1) m = fmaxf(m, __shfl_xor(m, k));
            const float p = __expf(l - m);
            float s = p;
#pragma unroll
            for (int k = 16; k >= 1; k >>= 1) s += __shfl_xor(s, k);
            const float c = p / s;

#pragma unroll
            for (int e = 0; e < E_DIM; ++e) Sacc[bb][e] = fmaf(c, uh[bb][e], Sacc[bb][e]);
        }
    }

#pragma unroll
    for (int bb = 0; bb < 4; ++bb) {
        float4* pv = (float4*)(partial + (size_t)chunk * BJE
                               + ((size_t)((bbase + bb) * J_DIM + j)) * E_DIM);
        pv[0] = make_float4(Sacc[bb][0],  Sacc[bb][1],  Sacc[bb][2],  Sacc[bb][3]);
        pv[1] = make_float4(Sacc[bb][4],  Sacc[bb][5],  Sacc[bb][6],  Sacc[bb][7]);
        pv[2] = make_float4(Sacc[bb][8],  Sacc[bb][9],  Sacc[bb][10], Sacc[bb][11]);
        pv[3] = make_float4(Sacc[bb][12], Sacc[bb][13], Sacc[bb][14], Sacc[bb][15]);
    }
}

// Sum partials over chunks (8 independent accumulators), then squash.
__global__ __launch_bounds__(128) void reduce_squash(
    const float* __restrict__ partial, float* __restrict__ Vacc,
    float* __restrict__ out, const int nc, const int final_it)
{
    const int t = blockIdx.x * blockDim.x + threadIdx.x;  // 0..BJE-1
    float a0=0.f,a1=0.f,a2=0.f,a3=0.f,a4=0.f,a5=0.f,a6=0.f,a7=0.f;
    for (int c = 0; c < nc; c += 8) {
        a0 += partial[(size_t)(c+0) * BJE + t];
        a1 += partial[(size_t)(c+1) * BJE + t];
        a2 += partial[(size_t)(c+2) * BJE + t];
        a3 += partial[(size_t)(c+3) * BJE + t];
        a4 += partial[(size_t)(c+4) * BJE + t];
        a5 += partial[(size_t)(c+5) * BJE + t];
        a6 += partial[(size_t)(c+6) * BJE + t];
        a7 += partial[(size_t)(c+7) * BJE + t];
    }
    const float acc = ((a0+a1)+(a2+a3)) + ((a4+a5)+(a6+a7));

    float s2 = acc * acc;
#pragma unroll
    for (int k = 8; k >= 1; k >>= 1) s2 += __shfl_xor(s2, k);  // reduce over e
    const float scale = s2 / (1.f + s2) * rsqrtf(s2 + 1e-7f);
    const float v = scale * acc;
    if (final_it) out[t] = v;
    else Vacc[t] += v;
}

// ---------------- fallback (small ws): round-4 LDS kernel, NC=128 ----------------
template <int NC>
__global__ __launch_bounds__(256, 4) void caps_pass_lds(
    const float* __restrict__ x, const float* __restrict__ W,
    const float* __restrict__ b0, const float* __restrict__ Vacc,
    float* __restrict__ partial)
{
    constexpr int CH = I_DIM / NC;
    const int tid = threadIdx.x, hw = tid >> 5, j = tid & 31;
    const int bx = blockIdx.x;
    const int chunk = bx & (NC - 1);
    const int bg = bx / NC;
    const int b = bg * 8 + hw;

    __shared__ float Ws[2][TILEF];
    int dstf[4];
#pragma unroll
    for (int r = 0; r < 4; ++r) {
        const int g = r * 256 + tid;
        dstf[r] = (g >> 5) * ROWF + (g & 31) * 4;
    }
    const int i0 = chunk * CH;
    float4 stg[4];
    {
        const float4* src = (const float4*)(W + (size_t)i0 * WTILE);
#pragma unroll
        for (int r = 0; r < 4; ++r) stg[r] = src[r * 256 + tid];
    }
    float vacc[E_DIM];
    {
        const float* vp = Vacc + ((size_t)(b * J_DIM + j)) * E_DIM;
#pragma unroll
        for (int e = 0; e < E_DIM; ++e) vacc[e] = vp[e];
    }
    float Sacc[E_DIM];
#pragma unroll
    for (int e = 0; e < E_DIM; ++e) Sacc[e] = 0.f;

    for (int ii = 0; ii < CH; ++ii) {
        float* wbuf = &Ws[ii & 1][0];
#pragma unroll
        for (int r = 0; r < 4; ++r) *(float4*)&wbuf[dstf[r]] = stg[r];
        __syncthreads();
        if (ii + 1 < CH) {
            const float4* src = (const float4*)(W + (size_t)(i0 + ii + 1) * WTILE);
#pragma unroll
            for (int r = 0; r < 4; ++r) stg[r] = src[r * 256 + tid];
        }
        const int i = i0 + ii;
        const float* xp = x + ((size_t)b * I_DIM + i) * D_IN;
        const float4 xa = *(const float4*)xp;
        const float4 xb4 = *(const float4*)(xp + 4);
        const float xd[8] = {xa.x, xa.y, xa.z, xa.w, xb4.x, xb4.y, xb4.z, xb4.w};
        float uh[E_DIM];
#pragma unroll
        for (int e = 0; e < E_DIM; ++e) uh[e] = 0.f;
        const float* wr = &wbuf[j * ROWF];
#pragma unroll
        for (int d = 0; d < D_IN; ++d) {
            const float4 w0 = *(const float4*)(wr + d * 16 + 0);
            const float4 w1 = *(const float4*)(wr + d * 16 + 4);
            const float4 w2 = *(const float4*)(wr + d * 16 + 8);
            const float4 w3 = *(const float4*)(wr + d * 16 + 12);
            const float xv = xd[d];
            uh[0]=fmaf(xv,w0.x,uh[0]);   uh[1]=fmaf(xv,w0.y,uh[1]);
            uh[2]=fmaf(xv,w0.z,uh[2]);   uh[3]=fmaf(xv,w0.w,uh[3]);
            uh[4]=fmaf(xv,w1.x,uh[4]);   uh[5]=fmaf(xv,w1.y,uh[5]);
            uh[6]=fmaf(xv,w1.z,uh[6]);   uh[7]=fmaf(xv,w1.w,uh[7]);
            uh[8]=fmaf(xv,w2.x,uh[8]);   uh[9]=fmaf(xv,w2.y,uh[9]);
            uh[10]=fmaf(xv,w2.z,uh[10]); uh[11]=fmaf(xv,w2.w,uh[11]);
            uh[12]=fmaf(xv,w3.x,uh[12]); uh[13]=fmaf(xv,w3.y,uh[13]);
            uh[14]=fmaf(xv,w3.z,uh[14]); uh[15]=fmaf(xv,w3.w,uh[15]);
        }
        float l = b0[i * J_DIM + j];
#pragma unroll
        for (int e = 0; e < E_DIM; ++e) l = fmaf(vacc[e], uh[e], l);
        float m = l;
#pragma unroll
        for (int k = 16; k >= 1; k >>= 1) m = fmaxf(m, __shfl_xor(m, k));
        const float p = __expf(l - m);
        float s = p;
#pragma unroll
        for (int k = 16; k >= 1; k >>= 1) s += __shfl_xor(s, k);
        const float c = p / s;
#pragma unroll
        for (int e = 0; e < E_DIM; ++e) Sacc[e] = fmaf(c, uh[e], Sacc[e]);
    }
    float* pp = partial + ((size_t)chunk * BJE) + ((size_t)(b * J_DIM + j)) * E_DIM;
    float4* pv = (float4*)pp;
    pv[0] = make_float4(Sacc[0],  Sacc[1],  Sacc[2],  Sacc[3]);
    pv[1] = make_float4(Sacc[4],  Sacc[5],  Sacc[6],  Sacc[7]);
    pv[2] = make_float4(Sacc[8],  Sacc[9],  Sacc[10], Sacc[11]);
    pv[3] = make_float4(Sacc[12], Sacc[13], Sacc[14], Sacc[15]);
}

extern "C" void kernel_launch(void* const* d_in, const int* in_sizes, int n_in,
                              void* d_out, int out_size, void* d_ws, size_t ws_size,
                              hipStream_t stream) {
    const float* x  = (const float*)d_in[0];   // [64,2304,8]
    const float* W  = (const float*)d_in[1];   // [2304,32,8,16]
    const float* b0 = (const float*)d_in[2];   // [2304,32]
    float* out = (float*)d_out;                // [64,32,16]

    const size_t need256 = ((size_t)256 + 1) * BJE * sizeof(float);  // 33.7 MB
    const size_t need128 = ((size_t)128 + 1) * BJE * sizeof(float);  // 16.9 MB

    if (ws_size >= need256) {
        float* partial = (float*)d_ws;
        float* Vacc    = partial + (size_t)256 * BJE;
        hipMemsetAsync(Vacc, 0, BJE * sizeof(float), stream);
        for (int it = 0; it < 3; ++it) {
            caps_pass_v5<<<NC5, 512, 0, stream>>>(x, W, b0, Vacc, partial);
            reduce_squash<<<BJE / 128, 128, 0, stream>>>(partial, Vacc, out, 256, it == 2 ? 1 : 0);
        }
    } else if (ws_size >= need128) {
        float* partial = (float*)d_ws;
        float* Vacc    = partial + (size_t)128 * BJE;
        hipMemsetAsync(Vacc, 0, BJE * sizeof(float), stream);
        for (int it = 0; it < 3; ++it) {
            caps_pass_lds<128><<<1024, 256, 0, stream>>>(x, W, b0, Vacc, partial);
            reduce_squash<<<BJE / 128, 128, 0, stream>>>(partial, Vacc, out, 128, it == 2 ? 1 : 0);
        }
    }
}